// Round 1
// baseline (199.506 us; speedup 1.0000x reference)
//
#include <hip/hip_runtime.h>
#include <math.h>

// ---- problem constants (fixed by reference setup) ----
constexpr int Bc    = 4;
constexpr int Nc    = 1024;
constexpr int SEQc  = 512;
constexpr int FOURc = 257;            // rfft length
constexpr int NTc   = Bc * Nc * FOURc; // 1,052,672 total graph nodes
constexpr int NSMALL = 1024;          // nodes touched by real edges
constexpr int F1c   = 30;             // H1*C1
constexpr int Rr    = 4;              // rows (b,n) per block in k_main
constexpr float NEG_SLOPE = 0.2f;

#define DEVFN static __device__ __forceinline__

DEVFN float atomAddF(float* p, float v) {
#if defined(__HIP_DEVICE_COMPILE__)
  return unsafeAtomicAdd(p, v);   // hw global_atomic_add_f32 on gfx950
#else
  return 0.f;
#endif
}

// ---------------- K0: cos table ct[t*257+k] = cos(2*pi*k*t/512) ----------------
__global__ void k_table(float* __restrict__ ct) {
  int i = blockIdx.x * 256 + threadIdx.x;
  if (i >= SEQc * FOURc) return;
  int t = i / FOURc, k = i - t * FOURc;
  int m = (t * k) & (SEQc - 1);     // exact arg reduction mod 512
  ct[i] = cosf((float)m * (6.283185307179586f / 512.0f));
}

// self-loop-only node value: v = elu(xf@W1 + b1) @ W2 + b2
DEVFN float node_v(float xo, float xp,
                   const float* w1s, const float* b1s, const float* w2s, float b2v) {
  float s = 0.f;
#pragma unroll
  for (int jj = 0; jj < F1c; ++jj) {
    float h = fmaf(xo, w1s[jj], fmaf(xp, w1s[F1c + jj], b1s[jj]));
    float e = h > 0.f ? h : (expf(h) - 1.f);
    s = fmaf(e, w2s[jj], s);
  }
  return s + b2v;
}

// ---------------- K1: rfft(real) + fused self-loop GAT pipeline ----------------
__global__ __launch_bounds__(64) void k_main(
    const float* __restrict__ occ, const float* __restrict__ prc,
    const float* __restrict__ ct,
    const float* __restrict__ W1, const float* __restrict__ b1,
    const float* __restrict__ W2, const float* __restrict__ b2,
    float* __restrict__ v, float* __restrict__ xfs) {
  __shared__ float so[Rr][SEQc];
  __shared__ float sp[Rr][SEQc];
  __shared__ float w1s[2 * F1c], b1s[F1c], w2s[F1c];
  const int lane = threadIdx.x;
  const int row0 = blockIdx.x * Rr;

  for (int j = 0; j < Rr; ++j) {
    const float* po = occ + (size_t)(row0 + j) * SEQc;
    const float* pp = prc + (size_t)(row0 + j) * SEQc;
    for (int idx = lane; idx < SEQc; idx += 64) {
      so[j][idx] = po[idx];
      sp[j][idx] = pp[idx];
    }
  }
  if (lane < F1c) {
    w1s[lane] = W1[lane];
    w1s[F1c + lane] = W1[F1c + lane];
    b1s[lane] = b1[lane];
    w2s[lane] = W2[lane];
  }
  __syncthreads();
  const float b2v = b2[0];

  float acco[Rr][4] = {};
  float accp[Rr][4] = {};

  for (int t = 0; t < SEQc; t += 4) {
    float ov[Rr][4], pv[Rr][4];
#pragma unroll
    for (int j = 0; j < Rr; ++j) {
      float4 a = *reinterpret_cast<const float4*>(&so[j][t]);
      float4 bq = *reinterpret_cast<const float4*>(&sp[j][t]);
      ov[j][0] = a.x; ov[j][1] = a.y; ov[j][2] = a.z; ov[j][3] = a.w;
      pv[j][0] = bq.x; pv[j][1] = bq.y; pv[j][2] = bq.z; pv[j][3] = bq.w;
    }
#pragma unroll
    for (int i = 0; i < 4; ++i) {
      const float* crow = ct + (size_t)(t + i) * FOURc + lane;
      float c0 = crow[0], c1 = crow[64], c2 = crow[128], c3 = crow[192];
#pragma unroll
      for (int j = 0; j < Rr; ++j) {
        float o = ov[j][i], p = pv[j][i];
        acco[j][0] = fmaf(c0, o, acco[j][0]);
        acco[j][1] = fmaf(c1, o, acco[j][1]);
        acco[j][2] = fmaf(c2, o, acco[j][2]);
        acco[j][3] = fmaf(c3, o, acco[j][3]);
        accp[j][0] = fmaf(c0, p, accp[j][0]);
        accp[j][1] = fmaf(c1, p, accp[j][1]);
        accp[j][2] = fmaf(c2, p, accp[j][2]);
        accp[j][3] = fmaf(c3, p, accp[j][3]);
      }
    }
  }

  for (int j = 0; j < Rr; ++j) {
#pragma unroll
    for (int q = 0; q < 4; ++q) {
      int k = q * 64 + lane;
      int node = (row0 + j) * FOURc + k;
      float xo = acco[j][q], xp = accp[j][q];
      v[node] = node_v(xo, xp, w1s, b1s, w2s, b2v);
      if (node < NSMALL) { xfs[2 * node] = xo; xfs[2 * node + 1] = xp; }
    }
    // k = 256: cos column is (-1)^t, do it as a wave reduction
    float sgo = 0.f, sgp = 0.f;
#pragma unroll
    for (int m = 0; m < 8; ++m) {
      sgo += so[j][lane + 64 * m];
      sgp += sp[j][lane + 64 * m];
    }
    float sign = (lane & 1) ? -1.f : 1.f;
    sgo *= sign; sgp *= sign;
#pragma unroll
    for (int off = 32; off; off >>= 1) {
      sgo += __shfl_xor(sgo, off);
      sgp += __shfl_xor(sgp, off);
    }
    if (lane == 0) {
      int node = (row0 + j) * FOURc + 256;
      v[node] = node_v(sgo, sgp, w1s, b1s, w2s, b2v);
      if (node < NSMALL) { xfs[2 * node] = sgo; xfs[2 * node + 1] = sgp; }
    }
  }
}

// ---------------- small-graph kernels (nodes 0..1023) ----------------
__global__ void k_g1(const float* __restrict__ xfs,
                     const float* __restrict__ W1,
                     const float* __restrict__ as1, const float* __restrict__ ad1,
                     float* __restrict__ h1s, float* __restrict__ a1s, float* __restrict__ a1d,
                     float* __restrict__ den1, float* __restrict__ out1,
                     float* __restrict__ den2, float* __restrict__ out2) {
  int i = blockIdx.x * 256 + threadIdx.x;
  if (i >= NSMALL) return;
  float xo = xfs[2 * i], xp = xfs[2 * i + 1];
#pragma unroll
  for (int h = 0; h < 3; ++h) {
    float as = 0.f, ad = 0.f;
#pragma unroll
    for (int c = 0; c < 10; ++c) {
      int jj = h * 10 + c;
      float hv = fmaf(xo, W1[jj], xp * W1[F1c + jj]);
      h1s[i * F1c + jj] = hv;
      out1[i * F1c + jj] = 0.f;
      as = fmaf(hv, as1[jj], as);
      ad = fmaf(hv, ad1[jj], ad);
    }
    a1s[i * 3 + h] = as;
    a1d[i * 3 + h] = ad;
    den1[i * 3 + h] = 0.f;
  }
  den2[i] = 0.f;
  out2[i] = 0.f;
}

DEVFN void edge_sd(const int* ei, int E, int e, int& src, int& dst) {
  if (e < E) { src = ei[e]; dst = ei[E + e]; }
  else       { src = dst = e - E; }   // self loops
}

__global__ void k_e1a(const int* __restrict__ ei, int E,
                      const float* __restrict__ a1s, const float* __restrict__ a1d,
                      float* __restrict__ den1) {
  int e = blockIdx.x * 256 + threadIdx.x;
  if (e >= E + NSMALL) return;
  int src, dst; edge_sd(ei, E, e, src, dst);
#pragma unroll
  for (int h = 0; h < 3; ++h) {
    float x = a1s[src * 3 + h] + a1d[dst * 3 + h];
    x = x > 0.f ? x : NEG_SLOPE * x;
    atomAddF(&den1[dst * 3 + h], expf(x));
  }
}

__global__ void k_e1b(const int* __restrict__ ei, int E,
                      const float* __restrict__ a1s, const float* __restrict__ a1d,
                      const float* __restrict__ den1, const float* __restrict__ h1s,
                      float* __restrict__ out1) {
  int e = blockIdx.x * 256 + threadIdx.x;
  if (e >= E + NSMALL) return;
  int src, dst; edge_sd(ei, E, e, src, dst);
#pragma unroll
  for (int h = 0; h < 3; ++h) {
    float x = a1s[src * 3 + h] + a1d[dst * 3 + h];
    x = x > 0.f ? x : NEG_SLOPE * x;
    float alpha = expf(x) / den1[dst * 3 + h];
#pragma unroll
    for (int c = 0; c < 10; ++c) {
      int jj = h * 10 + c;
      atomAddF(&out1[dst * F1c + jj], alpha * h1s[src * F1c + jj]);
    }
  }
}

__global__ void k_g5(const float* __restrict__ out1, const float* __restrict__ b1,
                     const float* __restrict__ W2,
                     const float* __restrict__ as2, const float* __restrict__ ad2,
                     float* __restrict__ h2s, float* __restrict__ a2s, float* __restrict__ a2d) {
  int i = blockIdx.x * 256 + threadIdx.x;
  if (i >= NSMALL) return;
  float h2 = 0.f;
#pragma unroll
  for (int jj = 0; jj < F1c; ++jj) {
    float x2 = out1[i * F1c + jj] + b1[jj];
    x2 = x2 > 0.f ? x2 : (expf(x2) - 1.f);
    h2 = fmaf(x2, W2[jj], h2);
  }
  h2s[i] = h2;
  a2s[i] = h2 * as2[0];
  a2d[i] = h2 * ad2[0];
}

__global__ void k_e2a(const int* __restrict__ ei, int E,
                      const float* __restrict__ a2s, const float* __restrict__ a2d,
                      float* __restrict__ den2) {
  int e = blockIdx.x * 256 + threadIdx.x;
  if (e >= E + NSMALL) return;
  int src, dst; edge_sd(ei, E, e, src, dst);
  float x = a2s[src] + a2d[dst];
  x = x > 0.f ? x : NEG_SLOPE * x;
  atomAddF(&den2[dst], expf(x));
}

__global__ void k_e2b(const int* __restrict__ ei, int E,
                      const float* __restrict__ a2s, const float* __restrict__ a2d,
                      const float* __restrict__ den2, const float* __restrict__ h2s,
                      float* __restrict__ out2) {
  int e = blockIdx.x * 256 + threadIdx.x;
  if (e >= E + NSMALL) return;
  int src, dst; edge_sd(ei, E, e, src, dst);
  float x = a2s[src] + a2d[dst];
  x = x > 0.f ? x : NEG_SLOPE * x;
  float alpha = expf(x) / den2[dst];
  atomAddF(&out2[dst], alpha * h2s[src]);
}

// ---------------- decode: out[row] = sum_k value(node) * dec_W[k] + dec_b ----------------
__global__ void k_dec(const float* __restrict__ v, const float* __restrict__ out2,
                      const float* __restrict__ b2,
                      const float* __restrict__ decW, const float* __restrict__ decb,
                      float* __restrict__ out) {
  int gid = blockIdx.x * 256 + threadIdx.x;
  int row = gid >> 6;
  int lane = gid & 63;
  if (row >= Bc * Nc) return;
  float b2v = b2[0];
  float s = 0.f;
  for (int k = lane; k < FOURc; k += 64) {
    int node = row * FOURc + k;
    float val = (node < NSMALL) ? (out2[node] + b2v) : v[node];
    s = fmaf(val, decW[k], s);
  }
#pragma unroll
  for (int off = 32; off; off >>= 1) s += __shfl_xor(s, off);
  if (lane == 0) out[row] = s + decb[0];
}

// ---------------- host launcher ----------------
extern "C" void kernel_launch(void* const* d_in, const int* in_sizes, int n_in,
                              void* d_out, int out_size, void* d_ws, size_t ws_size,
                              hipStream_t stream) {
  const float* occ  = (const float*)d_in[0];
  const float* prc  = (const float*)d_in[1];
  const int*   ei   = (const int*)d_in[2];
  const float* W1   = (const float*)d_in[3];
  const float* as1  = (const float*)d_in[4];
  const float* ad1  = (const float*)d_in[5];
  const float* b1   = (const float*)d_in[6];
  const float* W2   = (const float*)d_in[7];
  const float* as2  = (const float*)d_in[8];
  const float* ad2  = (const float*)d_in[9];
  const float* b2   = (const float*)d_in[10];
  const float* decW = (const float*)d_in[11];
  const float* decb = (const float*)d_in[12];
  const int E = in_sizes[2] / 2;

  float* ws = (float*)d_ws;
  float* v    = ws;                  // NTc
  float* ct   = v + NTc;             // 512*257
  float* xfs  = ct + SEQc * FOURc;   // 1024*2
  float* h1s  = xfs + 2 * NSMALL;    // 1024*30
  float* a1s  = h1s + NSMALL * F1c;  // 1024*3
  float* a1d  = a1s + NSMALL * 3;
  float* den1 = a1d + NSMALL * 3;
  float* out1 = den1 + NSMALL * 3;   // 1024*30
  float* h2s  = out1 + NSMALL * F1c;
  float* a2s  = h2s + NSMALL;
  float* a2d  = a2s + NSMALL;
  float* den2 = a2d + NSMALL;
  float* out2 = den2 + NSMALL;

  // K0: cos table
  k_table<<<(SEQc * FOURc + 255) / 256, 256, 0, stream>>>(ct);

  // K1: rfft + fused pointwise GAT (self-loop path) for all nodes
  k_main<<<(Bc * Nc) / Rr, 64, 0, stream>>>(occ, prc, ct, W1, b1, W2, b2, v, xfs);

  // small graph: layer 1
  k_g1<<<NSMALL / 256, 256, 0, stream>>>(xfs, W1, as1, ad1, h1s, a1s, a1d, den1, out1, den2, out2);
  int eblocks = (E + NSMALL + 255) / 256;
  k_e1a<<<eblocks, 256, 0, stream>>>(ei, E, a1s, a1d, den1);
  k_e1b<<<eblocks, 256, 0, stream>>>(ei, E, a1s, a1d, den1, h1s, out1);
  // layer 2
  k_g5<<<NSMALL / 256, 256, 0, stream>>>(out1, b1, W2, as2, ad2, h2s, a2s, a2d);
  k_e2a<<<eblocks, 256, 0, stream>>>(ei, E, a2s, a2d, den2);
  k_e2b<<<eblocks, 256, 0, stream>>>(ei, E, a2s, a2d, den2, h2s, out2);

  // decode
  k_dec<<<(Bc * Nc * 64 + 255) / 256, 256, 0, stream>>>(v, out2, b2, decW, decb, (float*)d_out);
}

// Round 2
// 149.871 us; speedup vs baseline: 1.3312x; 1.3312x over previous
//
#include <hip/hip_runtime.h>
#include <math.h>

// ---- problem constants (fixed by reference setup) ----
constexpr int Bc    = 4;
constexpr int Nc    = 1024;
constexpr int SEQc  = 512;
constexpr int FOURc = 257;              // rfft output length
constexpr int NROWS = Bc * Nc;          // 4096 (b,n) rows
constexpr int NTc   = NROWS * FOURc;    // 1,052,672 graph nodes
constexpr int NSMALL = 1024;            // nodes touched by real edges
constexpr int F1c   = 30;               // H1*C1
constexpr int TT    = 256;              // folded t length (t=0..255)
constexpr float NEG_SLOPE = 0.2f;

#define DEVFN static __device__ __forceinline__

DEVFN float atomAddF(float* p, float v) {
#if defined(__HIP_DEVICE_COMPILE__)
  return unsafeAtomicAdd(p, v);   // hw global_atomic_add_f32 on gfx950
#else
  return 0.f;
#endif
}

// ------- K0: cos table ct[t*256+k] = cos(2*pi*k*t/512), t,k in [0,256) -------
//         + zero the atomic accumulators (den1|num1|den2|num2 contiguous)
__global__ __launch_bounds__(256) void k_table(float* __restrict__ ct,
                                               float* __restrict__ zbuf, int zn) {
  int i = blockIdx.x * 256 + threadIdx.x;
  if (i < TT * 256) {
    int t = i >> 8, k = i & 255;
    int m = (t * k) & (SEQc - 1);       // exact arg reduction mod 512
    ct[i] = cosf((float)m * (6.283185307179586f / 512.0f));
  }
  if (i < zn) zbuf[i] = 0.f;
}

// self-loop-only node value: v = elu(xf@W1 + b1) @ W2 + b2
DEVFN float node_v(float xo, float xp,
                   const float* w1s, const float* b1s, const float* w2s, float b2v) {
  float s = 0.f;
#pragma unroll
  for (int jj = 0; jj < F1c; ++jj) {
    float h = fmaf(xo, w1s[jj], fmaf(xp, w1s[F1c + jj], b1s[jj]));
    float e = h > 0.f ? h : (__expf(h) - 1.f);
    s = fmaf(e, w2s[jj], s);
  }
  return s + b2v;
}

// layer-1 prep for small-graph nodes (was k_g1), done inline in block 0
DEVFN void small_prep(int node, float xo, float xp,
                      const float* w1s, const float* s1, const float* d1,
                      float* h1s, float* a1s, float* a1d) {
#pragma unroll
  for (int h = 0; h < 3; ++h) {
    float as = 0.f, ad = 0.f;
#pragma unroll
    for (int c = 0; c < 10; ++c) {
      int jj = h * 10 + c;
      float hv = fmaf(xo, w1s[jj], xp * w1s[F1c + jj]);
      h1s[node * F1c + jj] = hv;
      as = fmaf(hv, s1[jj], as);
      ad = fmaf(hv, d1[jj], ad);
    }
    a1s[node * 3 + h] = as;
    a1d[node * 3 + h] = ad;
  }
}

// ------- K1: folded cos-transform + fused self-loop GAT, 4 waves/block -------
__global__ __launch_bounds__(256) void k_main(
    const float* __restrict__ occ, const float* __restrict__ prc,
    const float* __restrict__ ct,
    const float* __restrict__ W1, const float* __restrict__ b1,
    const float* __restrict__ W2, const float* __restrict__ b2,
    const float* __restrict__ as1, const float* __restrict__ ad1,
    float* __restrict__ v,
    float* __restrict__ h1s, float* __restrict__ a1s, float* __restrict__ a1d) {
  __shared__ float y[4][TT][2];         // folded inputs, per wave-row
  __shared__ float wl[192];             // W1(60) b1(30) W2(30) as1(30) ad1(30)
  const int tid  = threadIdx.x;
  const int lane = tid & 63;
  const int wid  = tid >> 6;
  const int row  = blockIdx.x * 4 + wid;
  const float* ro = occ + (size_t)row * SEQc;
  const float* rp = prc + (size_t)row * SEQc;

  // stage folded y[t] = x[t] + x[512-t] (t=0 -> x[0]); per-wave, no barrier needed
  for (int t = lane; t < TT; t += 64) {
    float yo, yp;
    if (t == 0) { yo = ro[0]; yp = rp[0]; }
    else        { yo = ro[t] + ro[SEQc - t]; yp = rp[t] + rp[SEQc - t]; }
    y[wid][t][0] = yo;
    y[wid][t][1] = yp;
  }
  if      (tid < 60)  wl[tid] = W1[tid];
  else if (tid < 90)  wl[tid] = b1[tid - 60];
  else if (tid < 120) wl[tid] = W2[tid - 90];
  else if (tid < 150) wl[tid] = as1[tid - 120];
  else if (tid < 180) wl[tid] = ad1[tid - 150];
  __syncthreads();
  const float* w1s = wl;
  const float* b1s = wl + 60;
  const float* w2s = wl + 90;
  const float* s1  = wl + 120;
  const float* d1  = wl + 150;

  // main loop: lane owns k = 4*lane+q, q=0..3; k=256 via (-1)^t running sum
  float acco[4] = {0.f, 0.f, 0.f, 0.f};
  float accp[4] = {0.f, 0.f, 0.f, 0.f};
  float s256o = 0.f, s256p = 0.f;
  const float* ctl = ct + 4 * lane;
#pragma unroll 8
  for (int t = 0; t < TT; ++t) {
    float2 yv = *reinterpret_cast<const float2*>(&y[wid][t][0]);
    float4 c  = *reinterpret_cast<const float4*>(ctl + (size_t)t * 256);
    acco[0] = fmaf(c.x, yv.x, acco[0]);
    acco[1] = fmaf(c.y, yv.x, acco[1]);
    acco[2] = fmaf(c.z, yv.x, acco[2]);
    acco[3] = fmaf(c.w, yv.x, acco[3]);
    accp[0] = fmaf(c.x, yv.y, accp[0]);
    accp[1] = fmaf(c.y, yv.y, accp[1]);
    accp[2] = fmaf(c.z, yv.y, accp[2]);
    accp[3] = fmaf(c.w, yv.y, accp[3]);
    if (t & 1) { s256o -= yv.x; s256p -= yv.y; }
    else       { s256o += yv.x; s256p += yv.y; }
  }

  // epilogue
  const float x256o = ro[256], x256p = rp[256];
  const float b2v = b2[0];
  const bool smallrow = (row < 4);      // rows 0..3 hold all nodes < 1024
#pragma unroll
  for (int q = 0; q < 4; ++q) {
    int k = 4 * lane + q;
    float xo = acco[q] + ((q & 1) ? -x256o : x256o);
    float xp = accp[q] + ((q & 1) ? -x256p : x256p);
    int node = row * FOURc + k;
    v[node] = node_v(xo, xp, w1s, b1s, w2s, b2v);
    if (smallrow && node < NSMALL)
      small_prep(node, xo, xp, w1s, s1, d1, h1s, a1s, a1d);
  }
  // k = 256 (uniform across lanes; lane 0 stores)
  float xo = s256o + x256o;
  float xp = s256p + x256p;
  float vv = node_v(xo, xp, w1s, b1s, w2s, b2v);
  if (lane == 0) {
    int node = row * FOURc + 256;
    v[node] = vv;
    if (smallrow && node < NSMALL)
      small_prep(node, xo, xp, w1s, s1, d1, h1s, a1s, a1d);
  }
}

// ------- small-graph edge pass, layer 1: accumulate num & den (deferred div) -------
DEVFN void edge_sd(const int* ei, int E, int e, int& src, int& dst) {
  if (e < E) { src = ei[e]; dst = ei[E + e]; }
  else       { src = dst = e - E; }   // self loops
}

__global__ void k_e1(const int* __restrict__ ei, int E,
                     const float* __restrict__ a1s, const float* __restrict__ a1d,
                     const float* __restrict__ h1s,
                     float* __restrict__ den1, float* __restrict__ num1) {
  int e = blockIdx.x * 256 + threadIdx.x;
  if (e >= E + NSMALL) return;
  int src, dst; edge_sd(ei, E, e, src, dst);
#pragma unroll
  for (int h = 0; h < 3; ++h) {
    float x = a1s[src * 3 + h] + a1d[dst * 3 + h];
    x = x > 0.f ? x : NEG_SLOPE * x;
    float ex = __expf(x);
    atomAddF(&den1[dst * 3 + h], ex);
#pragma unroll
    for (int c = 0; c < 10; ++c) {
      int jj = h * 10 + c;
      atomAddF(&num1[dst * F1c + jj], ex * h1s[src * F1c + jj]);
    }
  }
}

// ------- between layers: x2 = elu(num1/den1 + b1); h2 = x2@W2; a2 scores -------
__global__ void k_g5(const float* __restrict__ num1, const float* __restrict__ den1,
                     const float* __restrict__ b1, const float* __restrict__ W2,
                     const float* __restrict__ as2, const float* __restrict__ ad2,
                     float* __restrict__ h2s, float* __restrict__ a2s,
                     float* __restrict__ a2d) {
  int i = blockIdx.x * 256 + threadIdx.x;
  if (i >= NSMALL) return;
  float h2 = 0.f;
#pragma unroll
  for (int jj = 0; jj < F1c; ++jj) {
    float x2 = num1[i * F1c + jj] / den1[i * 3 + jj / 10] + b1[jj];
    x2 = x2 > 0.f ? x2 : (__expf(x2) - 1.f);
    h2 = fmaf(x2, W2[jj], h2);
  }
  h2s[i] = h2;
  a2s[i] = h2 * as2[0];
  a2d[i] = h2 * ad2[0];
}

// ------- small-graph edge pass, layer 2 -------
__global__ void k_e2(const int* __restrict__ ei, int E,
                     const float* __restrict__ a2s, const float* __restrict__ a2d,
                     const float* __restrict__ h2s,
                     float* __restrict__ den2, float* __restrict__ num2) {
  int e = blockIdx.x * 256 + threadIdx.x;
  if (e >= E + NSMALL) return;
  int src, dst; edge_sd(ei, E, e, src, dst);
  float x = a2s[src] + a2d[dst];
  x = x > 0.f ? x : NEG_SLOPE * x;
  float ex = __expf(x);
  atomAddF(&den2[dst], ex);
  atomAddF(&num2[dst], ex * h2s[src]);
}

// ------- decode: out[row] = sum_k value(node)*dec_W[k] + dec_b -------
__global__ __launch_bounds__(256) void k_dec(
    const float* __restrict__ v,
    const float* __restrict__ num2, const float* __restrict__ den2,
    const float* __restrict__ b2,
    const float* __restrict__ decW, const float* __restrict__ decb,
    float* __restrict__ out) {
  int gid = blockIdx.x * 256 + threadIdx.x;
  int row = gid >> 6;
  int lane = gid & 63;
  if (row >= NROWS) return;
  float b2v = b2[0];
  float s = 0.f;
  for (int k = lane; k < FOURc; k += 64) {
    int node = row * FOURc + k;
    float val = (node < NSMALL) ? (num2[node] / den2[node] + b2v) : v[node];
    s = fmaf(val, decW[k], s);
  }
#pragma unroll
  for (int off = 32; off; off >>= 1) s += __shfl_xor(s, off);
  if (lane == 0) out[row] = s + decb[0];
}

// ---------------- host launcher ----------------
extern "C" void kernel_launch(void* const* d_in, const int* in_sizes, int n_in,
                              void* d_out, int out_size, void* d_ws, size_t ws_size,
                              hipStream_t stream) {
  const float* occ  = (const float*)d_in[0];
  const float* prc  = (const float*)d_in[1];
  const int*   ei   = (const int*)d_in[2];
  const float* W1   = (const float*)d_in[3];
  const float* as1  = (const float*)d_in[4];
  const float* ad1  = (const float*)d_in[5];
  const float* b1   = (const float*)d_in[6];
  const float* W2   = (const float*)d_in[7];
  const float* as2  = (const float*)d_in[8];
  const float* ad2  = (const float*)d_in[9];
  const float* b2   = (const float*)d_in[10];
  const float* decW = (const float*)d_in[11];
  const float* decb = (const float*)d_in[12];
  const int E = in_sizes[2] / 2;

  float* ws = (float*)d_ws;
  float* v    = ws;                      // NTc
  float* ct   = v + NTc;                 // 256*256
  float* h1s  = ct + TT * 256;           // 1024*30
  float* a1s  = h1s + NSMALL * F1c;      // 1024*3
  float* a1d  = a1s + NSMALL * 3;        // 1024*3
  // zero-init span (contiguous): den1 | num1 | den2 | num2
  float* den1 = a1d + NSMALL * 3;        // 1024*3
  float* num1 = den1 + NSMALL * 3;       // 1024*30
  float* den2 = num1 + NSMALL * F1c;     // 1024
  float* num2 = den2 + NSMALL;           // 1024
  const int zn = NSMALL * 3 + NSMALL * F1c + NSMALL + NSMALL;  // 35840
  float* h2s  = num2 + NSMALL;
  float* a2s  = h2s + NSMALL;
  float* a2d  = a2s + NSMALL;

  // K0: cos table + zero accumulators
  k_table<<<(TT * 256 + 255) / 256, 256, 0, stream>>>(ct, den1, zn);

  // K1: folded transform + pointwise GAT (all nodes) + layer-1 prep (block 0)
  k_main<<<NROWS / 4, 256, 0, stream>>>(occ, prc, ct, W1, b1, W2, b2, as1, ad1,
                                        v, h1s, a1s, a1d);

  const int eblocks = (E + NSMALL + 255) / 256;
  k_e1<<<eblocks, 256, 0, stream>>>(ei, E, a1s, a1d, h1s, den1, num1);
  k_g5<<<(NSMALL + 255) / 256, 256, 0, stream>>>(num1, den1, b1, W2, as2, ad2,
                                                 h2s, a2s, a2d);
  k_e2<<<eblocks, 256, 0, stream>>>(ei, E, a2s, a2d, h2s, den2, num2);

  k_dec<<<(NROWS * 64 + 255) / 256, 256, 0, stream>>>(v, num2, den2, b2,
                                                      decW, decb, (float*)d_out);
}

// Round 3
// 91.514 us; speedup vs baseline: 2.1801x; 1.6377x over previous
//
#include <hip/hip_runtime.h>
#include <math.h>

// ---- problem constants (fixed by reference setup) ----
constexpr int Bc    = 4;
constexpr int Nc    = 1024;
constexpr int SEQc  = 512;
constexpr int FOURc = 257;              // rfft output length
constexpr int NROWS = Bc * Nc;          // 4096 (b,n) rows
constexpr int NSMALL = 1024;            // nodes touched by real edges
constexpr int F1c   = 30;               // H1*C1
constexpr int TT    = 256;              // folded t length
constexpr float NEG_SLOPE = 0.2f;

#define DEVFN static __device__ __forceinline__

// ------- K_pre: blocks 0..63 build cos table; block 64 builds CSR -------
__global__ __launch_bounds__(1024) void k_pre(float* __restrict__ ct,
                                              const int* __restrict__ ei, int E,
                                              int* __restrict__ offs,
                                              int* __restrict__ srcs) {
  const int b = blockIdx.x, tid = threadIdx.x;
  if (b < 64) {
    int i = b * 1024 + tid;               // < 65536
    int t = i >> 8, k = i & 255;
    int m = (t * k) & (SEQc - 1);         // exact arg reduction mod 512
    ct[i] = cosf((float)m * (6.283185307179586f / 512.0f));
    return;
  }
  // ---- CSR build (single block, 1024 threads) ----
  __shared__ int cnt[1024];
  __shared__ int tmp[1024];
  const int tot = E + NSMALL;
  cnt[tid] = 0;
  __syncthreads();
  for (int e = tid; e < tot; e += 1024) {
    int dst = (e < E) ? ei[E + e] : (e - E);
    atomicAdd(&cnt[tid * 0 + dst], 1);    // LDS atomic
  }
  __syncthreads();
  int cv = cnt[tid];
  int val = cv;                            // inclusive scan (Hillis-Steele)
  for (int off = 1; off < 1024; off <<= 1) {
    tmp[tid] = val;
    __syncthreads();
    if (tid >= off) val += tmp[tid - off];
    __syncthreads();
  }
  int excl = val - cv;
  offs[tid] = excl;
  if (tid == 1023) offs[1024] = tot;
  cnt[tid] = excl;                         // reuse as scatter cursor
  __syncthreads();
  for (int e = tid; e < tot; e += 1024) {
    int src, dst;
    if (e < E) { src = ei[e]; dst = ei[E + e]; }
    else       { src = dst = e - E; }
    int pos = atomicAdd(&cnt[dst], 1);
    srcs[pos] = src;
  }
}

// self-loop-only node value: v = elu(xf@W1 + b1) @ W2 + b2
DEVFN float node_v(float xo, float xp,
                   const float* w1s, const float* b1s, const float* w2s, float b2v) {
  float s = 0.f;
#pragma unroll
  for (int jj = 0; jj < F1c; ++jj) {
    float h = fmaf(xo, w1s[jj], fmaf(xp, w1s[F1c + jj], b1s[jj]));
    float e = h > 0.f ? h : (__expf(h) - 1.f);
    s = fmaf(e, w2s[jj], s);
  }
  return s + b2v;
}

// layer-1 prep for small-graph nodes, done inline in block 0
DEVFN void small_prep(int node, float xo, float xp,
                      const float* w1s, const float* s1, const float* d1,
                      float* h1s, float* a1s, float* a1d) {
#pragma unroll
  for (int h = 0; h < 3; ++h) {
    float as = 0.f, ad = 0.f;
#pragma unroll
    for (int c = 0; c < 10; ++c) {
      int jj = h * 10 + c;
      float hv = fmaf(xo, w1s[jj], xp * w1s[F1c + jj]);
      h1s[node * F1c + jj] = hv;
      as = fmaf(hv, s1[jj], as);
      ad = fmaf(hv, d1[jj], ad);
    }
    a1s[node * 3 + h] = as;
    a1d[node * 3 + h] = ad;
  }
}

// ------- K_main: folded cos-transform + self-loop GAT + fused decode -------
__global__ __launch_bounds__(256) void k_main(
    const float* __restrict__ occ, const float* __restrict__ prc,
    const float* __restrict__ ct,
    const float* __restrict__ W1, const float* __restrict__ b1,
    const float* __restrict__ W2, const float* __restrict__ b2,
    const float* __restrict__ as1, const float* __restrict__ ad1,
    const float* __restrict__ decW, const float* __restrict__ decb,
    float* __restrict__ out, float* __restrict__ vsm,
    float* __restrict__ h1s, float* __restrict__ a1s, float* __restrict__ a1d) {
  __shared__ float y[4][TT][2];
  __shared__ float wl[192];               // W1(60) b1(30) W2(30) as1(30) ad1(30)
  const int tid  = threadIdx.x;
  const int lane = tid & 63;
  const int wid  = tid >> 6;
  const int row  = blockIdx.x * 4 + wid;
  const float* ro = occ + (size_t)row * SEQc;
  const float* rp = prc + (size_t)row * SEQc;

  for (int t = lane; t < TT; t += 64) {
    float yo, yp;
    if (t == 0) { yo = ro[0]; yp = rp[0]; }
    else        { yo = ro[t] + ro[SEQc - t]; yp = rp[t] + rp[SEQc - t]; }
    y[wid][t][0] = yo;
    y[wid][t][1] = yp;
  }
  if      (tid < 60)  wl[tid] = W1[tid];
  else if (tid < 90)  wl[tid] = b1[tid - 60];
  else if (tid < 120) wl[tid] = W2[tid - 90];
  else if (tid < 150) wl[tid] = as1[tid - 120];
  else if (tid < 180) wl[tid] = ad1[tid - 150];
  __syncthreads();
  const float* w1s = wl;
  const float* b1s = wl + 60;
  const float* w2s = wl + 90;
  const float* s1  = wl + 120;
  const float* d1  = wl + 150;

  float acco[4] = {0.f, 0.f, 0.f, 0.f};
  float accp[4] = {0.f, 0.f, 0.f, 0.f};
  float s256o = 0.f, s256p = 0.f;
  const float* ctl = ct + 4 * lane;
#pragma unroll 8
  for (int t = 0; t < TT; ++t) {
    float2 yv = *reinterpret_cast<const float2*>(&y[wid][t][0]);
    float4 c  = *reinterpret_cast<const float4*>(ctl + (size_t)t * 256);
    acco[0] = fmaf(c.x, yv.x, acco[0]);
    acco[1] = fmaf(c.y, yv.x, acco[1]);
    acco[2] = fmaf(c.z, yv.x, acco[2]);
    acco[3] = fmaf(c.w, yv.x, acco[3]);
    accp[0] = fmaf(c.x, yv.y, accp[0]);
    accp[1] = fmaf(c.y, yv.y, accp[1]);
    accp[2] = fmaf(c.z, yv.y, accp[2]);
    accp[3] = fmaf(c.w, yv.y, accp[3]);
    if (t & 1) { s256o -= yv.x; s256p -= yv.y; }
    else       { s256o += yv.x; s256p += yv.y; }
  }

  const float x256o = ro[256], x256p = rp[256];
  const float b2v = b2[0];
  const bool smallrow = (row < 4);        // rows 0..3 hold all nodes < 1024
  const float4 dw4 = *reinterpret_cast<const float4*>(decW + 4 * lane);
  const float dwq[4] = {dw4.x, dw4.y, dw4.z, dw4.w};
  float s = 0.f;                          // partial decode dot
#pragma unroll
  for (int q = 0; q < 4; ++q) {
    int k = 4 * lane + q;
    float xo = acco[q] + ((q & 1) ? -x256o : x256o);
    float xp = accp[q] + ((q & 1) ? -x256p : x256p);
    int node = row * FOURc + k;
    float vv = node_v(xo, xp, w1s, b1s, w2s, b2v);
    s = fmaf(vv, dwq[q], s);
    if (smallrow && node < NSMALL) {
      vsm[node] = vv;
      small_prep(node, xo, xp, w1s, s1, d1, h1s, a1s, a1d);
    }
  }
  // k = 256 (uniform across lanes)
  float xo = s256o + x256o;
  float xp = s256p + x256p;
  float v256 = node_v(xo, xp, w1s, b1s, w2s, b2v);
#pragma unroll
  for (int off = 32; off; off >>= 1) s += __shfl_xor(s, off);
  if (lane == 0) {
    out[row] = s + fmaf(v256, decW[256], decb[0]);
    int node = row * FOURc + 256;
    if (smallrow && node < NSMALL) {
      vsm[node] = v256;
      small_prep(node, xo, xp, w1s, s1, d1, h1s, a1s, a1d);
    }
  }
}

// ------- K_g1: layer-1 gather (one wave per dst) + layer-2 node prep -------
__global__ __launch_bounds__(256) void k_g1(
    const int* __restrict__ offs, const int* __restrict__ srcs,
    const float* __restrict__ a1s, const float* __restrict__ a1d,
    const float* __restrict__ h1s,
    const float* __restrict__ b1, const float* __restrict__ W2,
    const float* __restrict__ as2, const float* __restrict__ ad2,
    float* __restrict__ h2s, float* __restrict__ a2s, float* __restrict__ a2d) {
  const int lane = threadIdx.x & 63;
  const int dst  = blockIdx.x * 4 + (threadIdx.x >> 6);
  const int beg = offs[dst], end = offs[dst + 1];
  const float ad0 = a1d[dst * 3], ad1v = a1d[dst * 3 + 1], ad2v = a1d[dst * 3 + 2];
  float den[3] = {0.f, 0.f, 0.f};
  float num[F1c];
#pragma unroll
  for (int j = 0; j < F1c; ++j) num[j] = 0.f;

  for (int p = beg + lane; p < end; p += 64) {
    int src = srcs[p];
    const float* hs = h1s + src * F1c;
    float x0 = a1s[src * 3]     + ad0;
    float x1 = a1s[src * 3 + 1] + ad1v;
    float x2 = a1s[src * 3 + 2] + ad2v;
    x0 = x0 > 0.f ? x0 : NEG_SLOPE * x0;
    x1 = x1 > 0.f ? x1 : NEG_SLOPE * x1;
    x2 = x2 > 0.f ? x2 : NEG_SLOPE * x2;
    float e0 = __expf(x0), e1 = __expf(x1), e2 = __expf(x2);
    den[0] += e0; den[1] += e1; den[2] += e2;
#pragma unroll
    for (int c = 0; c < 10; ++c) {
      num[c]      = fmaf(e0, hs[c],      num[c]);
      num[10 + c] = fmaf(e1, hs[10 + c], num[10 + c]);
      num[20 + c] = fmaf(e2, hs[20 + c], num[20 + c]);
    }
  }
  // butterfly reduce 33 accumulators
#pragma unroll
  for (int h = 0; h < 3; ++h)
#pragma unroll
    for (int off = 32; off; off >>= 1) den[h] += __shfl_xor(den[h], off);
#pragma unroll
  for (int j = 0; j < F1c; ++j)
#pragma unroll
    for (int off = 32; off; off >>= 1) num[j] += __shfl_xor(num[j], off);

  if (lane == 0) {
    float h2 = 0.f;
#pragma unroll
    for (int jj = 0; jj < F1c; ++jj) {
      float x2 = num[jj] / den[jj / 10] + b1[jj];
      x2 = x2 > 0.f ? x2 : (__expf(x2) - 1.f);
      h2 = fmaf(x2, W2[jj], h2);
    }
    h2s[dst] = h2;
    a2s[dst] = h2 * as2[0];
    a2d[dst] = h2 * ad2[0];
  }
}

// ------- K_g2: layer-2 gather (one wave per dst) -> final node value -------
__global__ __launch_bounds__(256) void k_g2(
    const int* __restrict__ offs, const int* __restrict__ srcs,
    const float* __restrict__ a2s, const float* __restrict__ a2d,
    const float* __restrict__ h2s, const float* __restrict__ b2,
    float* __restrict__ val2) {
  const int lane = threadIdx.x & 63;
  const int dst  = blockIdx.x * 4 + (threadIdx.x >> 6);
  const int beg = offs[dst], end = offs[dst + 1];
  const float adv = a2d[dst];
  float den = 0.f, num = 0.f;
  for (int p = beg + lane; p < end; p += 64) {
    int src = srcs[p];
    float x = a2s[src] + adv;
    x = x > 0.f ? x : NEG_SLOPE * x;
    float ex = __expf(x);
    den += ex;
    num = fmaf(ex, h2s[src], num);
  }
#pragma unroll
  for (int off = 32; off; off >>= 1) {
    den += __shfl_xor(den, off);
    num += __shfl_xor(num, off);
  }
  if (lane == 0) val2[dst] = num / den + b2[0];
}

// ------- K_tail: correct decode for rows 0..3 -------
__global__ __launch_bounds__(256) void k_tail(
    const float* __restrict__ val2, const float* __restrict__ vsm,
    const float* __restrict__ decW, float* __restrict__ out) {
  const int lane = threadIdx.x & 63;
  const int r    = threadIdx.x >> 6;      // rows 0..3
  float c = 0.f;
  for (int k = lane; k < FOURc; k += 64) {
    int node = r * FOURc + k;
    if (node < NSMALL) c += (val2[node] - vsm[node]) * decW[k];
  }
#pragma unroll
  for (int off = 32; off; off >>= 1) c += __shfl_xor(c, off);
  if (lane == 0) out[r] += c;
}

// ---------------- host launcher ----------------
extern "C" void kernel_launch(void* const* d_in, const int* in_sizes, int n_in,
                              void* d_out, int out_size, void* d_ws, size_t ws_size,
                              hipStream_t stream) {
  const float* occ  = (const float*)d_in[0];
  const float* prc  = (const float*)d_in[1];
  const int*   ei   = (const int*)d_in[2];
  const float* W1   = (const float*)d_in[3];
  const float* as1  = (const float*)d_in[4];
  const float* ad1  = (const float*)d_in[5];
  const float* b1   = (const float*)d_in[6];
  const float* W2   = (const float*)d_in[7];
  const float* as2  = (const float*)d_in[8];
  const float* ad2  = (const float*)d_in[9];
  const float* b2   = (const float*)d_in[10];
  const float* decW = (const float*)d_in[11];
  const float* decb = (const float*)d_in[12];
  const int E = in_sizes[2] / 2;

  float* ws = (float*)d_ws;
  float* ct   = ws;                       // 65536
  float* h1s  = ct + TT * 256;            // 1024*30
  float* a1s  = h1s + NSMALL * F1c;       // 1024*3
  float* a1d  = a1s + NSMALL * 3;         // 1024*3
  float* h2s  = a1d + NSMALL * 3;         // 1024
  float* a2s  = h2s + NSMALL;             // 1024
  float* a2d  = a2s + NSMALL;             // 1024
  float* val2 = a2d + NSMALL;             // 1024
  float* vsm  = val2 + NSMALL;            // 1024
  int*   offs = (int*)(vsm + NSMALL);     // 1025
  int*   srcs = offs + 1032;              // E + 1024

  // K_pre: cos table (blocks 0..63) + CSR build (block 64)
  k_pre<<<65, 1024, 0, stream>>>(ct, ei, E, offs, srcs);

  // K_main: folded transform + pointwise GAT + fused decode (all rows)
  k_main<<<NROWS / 4, 256, 0, stream>>>(occ, prc, ct, W1, b1, W2, b2, as1, ad1,
                                        decW, decb, (float*)d_out, vsm,
                                        h1s, a1s, a1d);

  // small-graph gathers (no atomics)
  k_g1<<<NSMALL / 4, 256, 0, stream>>>(offs, srcs, a1s, a1d, h1s,
                                       b1, W2, as2, ad2, h2s, a2s, a2d);
  k_g2<<<NSMALL / 4, 256, 0, stream>>>(offs, srcs, a2s, a2d, h2s, b2, val2);

  // fix rows 0..3
  k_tail<<<1, 256, 0, stream>>>(val2, vsm, decW, (float*)d_out);
}